// Round 2
// baseline (749.968 us; speedup 1.0000x reference)
//
#include <hip/hip_runtime.h>
#include <stdint.h>
#include <stddef.h>

// ---- problem constants ----
#define NWIN   64
#define NTOK   64
#define CDIM   192
#define NHEAD  6
#define HDIM   32
constexpr float SCALE = 0.17677669529663687f;  // 32^-0.5

// ---- vector types ----
typedef float   f32x4  __attribute__((ext_vector_type(4)));
typedef float   fvec4  __attribute__((ext_vector_type(4)));
typedef __bf16  bfx8   __attribute__((ext_vector_type(8)));
typedef __bf16  bfx4   __attribute__((ext_vector_type(4)));

static __device__ __forceinline__ bfx8 pack8(fvec4 a, fvec4 b) {
  bfx8 r;
  r[0] = (__bf16)a[0]; r[1] = (__bf16)a[1]; r[2] = (__bf16)a[2]; r[3] = (__bf16)a[3];
  r[4] = (__bf16)b[0]; r[5] = (__bf16)b[1]; r[6] = (__bf16)b[2]; r[7] = (__bf16)b[3];
  return r;
}

// ---- LDS layout (bytes) ----
// qk   [64][392] bf16 : 0      .. 50176   (cols 0..383 used: q|k, pad 8)
// vT   [6*32][72] bf16: 50176  .. 77824   (v transposed per head, pad 8)
// pf   [64][68]  f32  : 77824  .. 95232   (raw scores)
// pb   [64][72]  bf16 : 95232  .. 104448  (softmaxed P)
// xb/ao[64][200] bf16 : 104448 .. 130048  (x staging, later attn-out; aliased)
#define LDS_BYTES 130048

__global__ void __launch_bounds__(512, 1)
wattn_fused(const float* __restrict__ x, const float* __restrict__ mask,
            const float* __restrict__ qkv_w, const float* __restrict__ qkv_b,
            const float* __restrict__ proj_w, const float* __restrict__ proj_b,
            float* __restrict__ out)
{
  extern __shared__ char smem[];
  __bf16* qk = (__bf16*)(smem);             // [64][392]
  __bf16* vT = (__bf16*)(smem + 50176);     // [192][72]  ( (h*32+d) x m )
  float*  pf = (float*)(smem + 77824);      // [64][68]
  __bf16* pb = (__bf16*)(smem + 95232);     // [64][72]
  __bf16* xb = (__bf16*)(smem + 104448);    // [64][200]
  __bf16* ao = xb;                          // alias: x dead after phase 2

  const int b    = blockIdx.x;
  const int tid  = threadIdx.x;
  const int wv   = tid >> 6;     // wave 0..7
  const int lane = tid & 63;
  const int r16  = lane & 15;
  const int q4   = lane >> 4;    // 0..3

  // ---------------- Phase 1: stage x[b] f32 -> bf16 LDS ----------------
  {
    const float* xg = x + (size_t)b * (NTOK * CDIM);
#pragma unroll
    for (int it = 0; it < 6; ++it) {
      int i   = tid + it * 512;        // 0..3071 float4-chunks
      int row = i / 48;
      int col = (i % 48) * 4;
      fvec4 v = *(const fvec4*)(xg + i * 4);
      bfx4 p; p[0] = (__bf16)v[0]; p[1] = (__bf16)v[1];
              p[2] = (__bf16)v[2]; p[3] = (__bf16)v[3];
      *(bfx4*)(xb + row * 200 + col) = p;
    }
  }
  __syncthreads();

  // ---------------- Phase 2: QKV = x @ qkv_w^T + qkv_b ----------------
  // out cols 0..575 ; col-tile ct (16 cols); wave owns ct == wv (mod 8)
  {
    f32x4 acc[5][4];
#pragma unroll
    for (int cl = 0; cl < 5; ++cl)
#pragma unroll
      for (int rt = 0; rt < 4; ++rt) acc[cl][rt] = (f32x4){0.f, 0.f, 0.f, 0.f};

    for (int k = 0; k < 6; ++k) {
      bfx8 af[4];
#pragma unroll
      for (int rt = 0; rt < 4; ++rt)
        af[rt] = *(const bfx8*)(xb + (rt * 16 + r16) * 200 + k * 32 + q4 * 8);
#pragma unroll
      for (int cl = 0; cl < 5; ++cl) {
        int ct = wv + cl * 8;
        if (ct < 36) {
          const float* wp = qkv_w + (size_t)(ct * 16 + r16) * 192 + k * 32 + q4 * 8;
          bfx8 bf = pack8(*(const fvec4*)wp, *(const fvec4*)(wp + 4));
#pragma unroll
          for (int rt = 0; rt < 4; ++rt)
            acc[cl][rt] = __builtin_amdgcn_mfma_f32_16x16x32_bf16(
                af[rt], bf, acc[cl][rt], 0, 0, 0);
        }
      }
    }
    // epilogue: bias, convert, store (q/k row-major; v transposed)
#pragma unroll
    for (int cl = 0; cl < 5; ++cl) {
      int ct = wv + cl * 8;
      if (ct < 36) {
        float bias = qkv_b[ct * 16 + r16];
        if (ct < 24) {  // q (ct<12) and k (12..23): row-major into qk
#pragma unroll
          for (int rt = 0; rt < 4; ++rt) {
#pragma unroll
            for (int r = 0; r < 4; ++r)
              qk[(rt * 16 + q4 * 4 + r) * 392 + ct * 16 + r16] =
                  (__bf16)(acc[cl][rt][r] + bias);
          }
        } else {        // v: write transposed vT[h*32+d][m], 4 contig m -> b64
          int h = (ct - 24) >> 1;
          int d = ((ct - 24) & 1) * 16 + r16;
#pragma unroll
          for (int rt = 0; rt < 4; ++rt) {
            bfx4 p;
#pragma unroll
            for (int r = 0; r < 4; ++r) p[r] = (__bf16)(acc[cl][rt][r] + bias);
            *(bfx4*)(vT + (h * 32 + d) * 72 + rt * 16 + q4 * 4) = p;
          }
        }
      }
    }
  }
  __syncthreads();

  // ---------------- Phase 3: attention per head ----------------
  const int wmask = b & (NWIN - 1);
  for (int h = 0; h < 6; ++h) {
    // 3a: raw scores = q @ k^T   (16 tiles, 1 MFMA each since K=32)
    {
      int nt = wv >> 1;
      bfx8 qf = *(const bfx8*)(qk + (nt * 16 + r16) * 392 + h * 32 + q4 * 8);
      f32x4 z = (f32x4){0.f, 0.f, 0.f, 0.f};
#pragma unroll
      for (int j = 0; j < 2; ++j) {
        int mt = (wv & 1) * 2 + j;
        bfx8 kf = *(const bfx8*)(qk + (mt * 16 + r16) * 392 + 192 + h * 32 + q4 * 8);
        f32x4 s = __builtin_amdgcn_mfma_f32_16x16x32_bf16(qf, kf, z, 0, 0, 0);
#pragma unroll
        for (int r = 0; r < 4; ++r)
          pf[(nt * 16 + q4 * 4 + r) * 68 + mt * 16 + r16] = s[r];
      }
    }
    __syncthreads();
    // 3b: wave-parallel softmax: 8 lanes per row, 8 vals per lane
    {
      int n  = tid >> 3;
      int s8 = (tid & 7) * 8;
      const float* mrow = mask + ((size_t)wmask * 64 + n) * 64 + s8;
      fvec4 m0 = *(const fvec4*)(mrow);
      fvec4 m1 = *(const fvec4*)(mrow + 4);
      float v[8];
#pragma unroll
      for (int i = 0; i < 4; ++i) v[i]     = pf[n * 68 + s8 + i]     * SCALE + m0[i];
#pragma unroll
      for (int i = 0; i < 4; ++i) v[4 + i] = pf[n * 68 + s8 + 4 + i] * SCALE + m1[i];
      float mx = v[0];
#pragma unroll
      for (int i = 1; i < 8; ++i) mx = fmaxf(mx, v[i]);
      mx = fmaxf(mx, __shfl_xor(mx, 1));
      mx = fmaxf(mx, __shfl_xor(mx, 2));
      mx = fmaxf(mx, __shfl_xor(mx, 4));
      float sum = 0.f;
#pragma unroll
      for (int i = 0; i < 8; ++i) { v[i] = __expf(v[i] - mx); sum += v[i]; }
      sum += __shfl_xor(sum, 1);
      sum += __shfl_xor(sum, 2);
      sum += __shfl_xor(sum, 4);
      float inv = 1.f / sum;
      bfx8 p;
#pragma unroll
      for (int i = 0; i < 8; ++i) p[i] = (__bf16)(v[i] * inv);
      *(bfx8*)(pb + n * 72 + s8) = p;
    }
    __syncthreads();
    // 3c: PV = P @ V  (8 tiles, one per wave, K=64 -> 2 MFMA)
    {
      int nt = wv >> 1, dt = wv & 1;
      f32x4 acc = (f32x4){0.f, 0.f, 0.f, 0.f};
#pragma unroll
      for (int kk = 0; kk < 2; ++kk) {
        bfx8 pa = *(const bfx8*)(pb + (nt * 16 + r16) * 72 + kk * 32 + q4 * 8);
        bfx8 vb = *(const bfx8*)(vT + (h * 32 + dt * 16 + r16) * 72 + kk * 32 + q4 * 8);
        acc = __builtin_amdgcn_mfma_f32_16x16x32_bf16(pa, vb, acc, 0, 0, 0);
      }
#pragma unroll
      for (int r = 0; r < 4; ++r)
        ao[(nt * 16 + q4 * 4 + r) * 200 + h * 32 + dt * 16 + r16] = (__bf16)acc[r];
    }
    __syncthreads();
  }

  // ---------------- Phase 4: out = ao @ proj_w^T + proj_b ----------------
  // 12 col-tiles x 2 row-halves = 24 units, 3 per wave
  {
    f32x4 acc[3][2];
#pragma unroll
    for (int u = 0; u < 3; ++u)
#pragma unroll
      for (int j = 0; j < 2; ++j) acc[u][j] = (f32x4){0.f, 0.f, 0.f, 0.f};

    for (int k = 0; k < 6; ++k) {
#pragma unroll
      for (int u = 0; u < 3; ++u) {
        int uid  = wv + u * 8;        // 0..23
        int ct   = uid % 12;
        int half = uid / 12;
        const float* wp = proj_w + (size_t)(ct * 16 + r16) * 192 + k * 32 + q4 * 8;
        bfx8 bf = pack8(*(const fvec4*)wp, *(const fvec4*)(wp + 4));
#pragma unroll
        for (int j = 0; j < 2; ++j) {
          int rt = half * 2 + j;
          bfx8 af = *(const bfx8*)(ao + (rt * 16 + r16) * 200 + k * 32 + q4 * 8);
          acc[u][j] = __builtin_amdgcn_mfma_f32_16x16x32_bf16(af, bf, acc[u][j], 0, 0, 0);
        }
      }
    }
    float* og = out + (size_t)b * (NTOK * CDIM);
#pragma unroll
    for (int u = 0; u < 3; ++u) {
      int uid  = wv + u * 8;
      int ct   = uid % 12;
      int half = uid / 12;
      float bias = proj_b[ct * 16 + r16];
#pragma unroll
      for (int j = 0; j < 2; ++j) {
        int rt = half * 2 + j;
#pragma unroll
        for (int r = 0; r < 4; ++r)
          og[(rt * 16 + q4 * 4 + r) * 192 + ct * 16 + r16] = acc[u][j][r] + bias;
      }
    }
  }
}

extern "C" void kernel_launch(void* const* d_in, const int* in_sizes, int n_in,
                              void* d_out, int out_size, void* d_ws, size_t ws_size,
                              hipStream_t stream) {
  (void)in_sizes; (void)n_in; (void)d_ws; (void)ws_size; (void)out_size;
  const float* x      = (const float*)d_in[0];
  const float* mask   = (const float*)d_in[1];
  const float* qkv_w  = (const float*)d_in[2];
  const float* qkv_b  = (const float*)d_in[3];
  const float* proj_w = (const float*)d_in[4];
  const float* proj_b = (const float*)d_in[5];
  float* out = (float*)d_out;

  hipFuncSetAttribute((const void*)wattn_fused,
                      hipFuncAttributeMaxDynamicSharedMemorySize, LDS_BYTES);
  wattn_fused<<<dim3(4096), dim3(512), LDS_BYTES, stream>>>(
      x, mask, qkv_w, qkv_b, proj_w, proj_b, out);
}